// Round 2
// baseline (1053.428 us; speedup 1.0000x reference)
//
#include <hip/hip_runtime.h>
#include <stdint.h>

#define NCn 4096
#define NPn 8192
#define Hn  128
#define En  500000
#define ELn 500000

typedef unsigned short u16;
using f32x4  = __attribute__((ext_vector_type(4))) float;
using bf16x8 = __attribute__((ext_vector_type(8))) short;

__device__ inline u16 f2bf(float f) {
  union { float f; uint32_t u; } v; v.f = f;
  uint32_t r = v.u + 0x7fffu + ((v.u >> 16) & 1u);   // RNE
  return (u16)(r >> 16);
}

// ---------------------------------------------------------------------------
// Weight transpose+convert: W[K][128] fp32 -> WT[128][K] bf16
// ---------------------------------------------------------------------------
__global__ __launch_bounds__(256) void wtrans(const float* __restrict__ W,
                                              u16* __restrict__ WT, int K) {
  int t = blockIdx.x * 256 + threadIdx.x;
  int kc8 = K >> 3;
  if (t >= 128 * kc8) return;
  int kc = t % kc8, n = t / kc8;
  u16 pk[8];
#pragma unroll
  for (int j = 0; j < 8; ++j) pk[j] = f2bf(W[(size_t)(kc * 8 + j) * 128 + n]);
  uint4 v;
  v.x = (uint32_t)pk[0] | ((uint32_t)pk[1] << 16);
  v.y = (uint32_t)pk[2] | ((uint32_t)pk[3] << 16);
  v.z = (uint32_t)pk[4] | ((uint32_t)pk[5] << 16);
  v.w = (uint32_t)pk[6] | ((uint32_t)pk[7] << 16);
  *(uint4*)&WT[(size_t)n * K + kc * 8] = v;
}

// ---------------------------------------------------------------------------
// CSR build: count -> exclusive scan -> fill
// ---------------------------------------------------------------------------
__global__ __launch_bounds__(256) void count_deg(const int* __restrict__ esrc,
                                                 const int* __restrict__ edst,
                                                 int* __restrict__ cntC,
                                                 int* __restrict__ cntP) {
  int i = blockIdx.x * 256 + threadIdx.x;
  if (i >= En) return;
  atomicAdd(&cntP[edst[i]], 1);
  atomicAdd(&cntC[esrc[i]], 1);
}

__global__ __launch_bounds__(256) void scan_excl(const int* __restrict__ cnt,
                                                 int* __restrict__ off,
                                                 int* __restrict__ cur, int n) {
  __shared__ int sh[257];
  int t = threadIdx.x;
  int chunk = n >> 8;
  int base = t * chunk;
  int s = 0;
  for (int i = 0; i < chunk; ++i) s += cnt[base + i];
  sh[t] = s;
  __syncthreads();
  if (t == 0) {
    int run = 0;
    for (int i = 0; i < 256; ++i) { int v = sh[i]; sh[i] = run; run += v; }
    sh[256] = run;
  }
  __syncthreads();
  int p = sh[t];
  for (int i = 0; i < chunk; ++i) {
    off[base + i] = p; cur[base + i] = p; p += cnt[base + i];
  }
  if (t == 255) off[n] = sh[256];
}

__global__ __launch_bounds__(256) void fill_adj(const int* __restrict__ esrc,
                                                const int* __restrict__ edst,
                                                int* __restrict__ curC,
                                                int* __restrict__ curP,
                                                int* __restrict__ adjC,
                                                int* __restrict__ adjP) {
  int i = blockIdx.x * 256 + threadIdx.x;
  if (i >= En) return;
  int s = esrc[i], d = edst[i];
  int p = atomicAdd(&curP[d], 1);
  adjP[p] = s;
  int q = atomicAdd(&curC[s], 1);
  adjC[q] = d;
}

// ---------------------------------------------------------------------------
// Split-K big projection GEMM: partial[c][M][128] = A[:, c*Kc:(c+1)*Kc] @ BT^T
// BM=32, BN=128, BK=64; 4 waves; register prefetch of BOTH A and B tiles so
// global/L2 latency hides under compute of the previous K-step.
// ---------------------------------------------------------------------------
__global__ __launch_bounds__(256) void gemm_big_sk(const float* __restrict__ A,
                                                   const u16* __restrict__ BT,
                                                   float* __restrict__ part,
                                                   int K, int Kc) {
  __shared__ __align__(16) u16 aL[32 * 64];    // [row][k] swizzled, 4KB
  __shared__ __align__(16) u16 bL[128 * 64];   // [n][k]   swizzled, 16KB
  const int t = threadIdx.x;
  const int wid = t >> 6, lane = t & 63;
  const int ln15 = lane & 15, lhi = lane >> 4;
  const int m0 = blockIdx.x * 32;
  const int kb0 = blockIdx.y * Kc;
  const size_t M128 = (size_t)gridDim.x * 32 * 128;

  f32x4 acc[2][2] = {};

  const int ar0 = t >> 4;            // A staging rows
  const int ac4 = t & 15;            // float4 col within 64-wide k tile
  const int nIter = Kc >> 6;

  float4 av[2];
  uint4  bv[4];
#pragma unroll
  for (int i = 0; i < 2; ++i)
    av[i] = *(const float4*)&A[(size_t)(m0 + ar0 + i * 16) * K + kb0 + ac4 * 4];
#pragma unroll
  for (int i = 0; i < 4; ++i) {
    int idx = t + i * 256, n = idx >> 3, sl = idx & 7;
    bv[i] = *(const uint4*)((const char*)BT + ((size_t)n * K + kb0) * 2 + sl * 16);
  }

  for (int it = 0; it < nIter; ++it) {
    __syncthreads();                 // prior compute done -> LDS reusable
    // ---- store prefetched A tile (fp32 regs -> bf16 LDS, swizzled) ----
#pragma unroll
    for (int i = 0; i < 2; ++i) {
      int row = ar0 + i * 16;
      int off = row * 128 + ((ac4 * 8) ^ ((row & 7) << 4));
      uint2 p;
      p.x = (uint32_t)f2bf(av[i].x) | ((uint32_t)f2bf(av[i].y) << 16);
      p.y = (uint32_t)f2bf(av[i].z) | ((uint32_t)f2bf(av[i].w) << 16);
      *(uint2*)((char*)aL + off) = p;
    }
    // ---- store prefetched B tile (regs -> LDS, swizzled) ----
#pragma unroll
    for (int i = 0; i < 4; ++i) {
      int idx = t + i * 256, n = idx >> 3, sl = idx & 7;
      *(uint4*)((char*)bL + n * 128 + ((sl * 16) ^ ((n & 7) << 4))) = bv[i];
    }
    // ---- issue next-iter loads (latency hides under barrier + MFMA) ----
    if (it + 1 < nIter) {
      const int k0 = kb0 + (it + 1) * 64;
#pragma unroll
      for (int i = 0; i < 2; ++i)
        av[i] = *(const float4*)&A[(size_t)(m0 + ar0 + i * 16) * K + k0 + ac4 * 4];
#pragma unroll
      for (int i = 0; i < 4; ++i) {
        int idx = t + i * 256, n = idx >> 3, sl = idx & 7;
        bv[i] = *(const uint4*)((const char*)BT + ((size_t)n * K + k0) * 2 + sl * 16);
      }
    }
    __syncthreads();
    // ---- compute: 2 k-substeps x 4 MFMA ----
#pragma unroll
    for (int ks = 0; ks < 2; ++ks) {
      const int kb = ks * 64 + lhi * 16;
      bf16x8 afr[2], bfr[2];
#pragma unroll
      for (int mi = 0; mi < 2; ++mi) {
        int r = mi * 16 + ln15;
        afr[mi] = *(const bf16x8*)((const char*)aL + r * 128 + (kb ^ ((r & 7) << 4)));
      }
#pragma unroll
      for (int ni = 0; ni < 2; ++ni) {
        int n = wid * 32 + ni * 16 + ln15;
        bfr[ni] = *(const bf16x8*)((const char*)bL + n * 128 + (kb ^ ((n & 7) << 4)));
      }
#pragma unroll
      for (int mi = 0; mi < 2; ++mi)
#pragma unroll
        for (int ni = 0; ni < 2; ++ni)
          acc[mi][ni] = __builtin_amdgcn_mfma_f32_16x16x32_bf16(afr[mi], bfr[ni],
                                                                acc[mi][ni], 0, 0, 0);
    }
  }
  // ---- write fp32 partial (no bias/addend here) ----
  float* P = part + (size_t)blockIdx.y * M128;
#pragma unroll
  for (int mi = 0; mi < 2; ++mi) {
#pragma unroll
    for (int ni = 0; ni < 2; ++ni) {
      int col = wid * 32 + ni * 16 + ln15;
#pragma unroll
      for (int r = 0; r < 4; ++r) {
        int row = m0 + mi * 16 + lhi * 4 + r;
        P[(size_t)row * 128 + col] = acc[mi][ni][r];
      }
    }
  }
}

// Combine split-K partials: out = sum_c part[c] + bias + addend
__global__ __launch_bounds__(256) void gemm_combine(const float* __restrict__ part,
                                                    const float* __restrict__ bias,
                                                    const float* __restrict__ addend,
                                                    float* __restrict__ out,
                                                    int M, int SK) {
  int i = blockIdx.x * 256 + threadIdx.x;   // float4 index
  int n4 = M * 32;
  if (i >= n4) return;
  size_t stride = (size_t)M * 128;
  f32x4 s = {};
  for (int c = 0; c < SK; ++c) s += *(const f32x4*)&part[c * stride + (size_t)i * 4];
  int col = (i * 4) & 127;
  f32x4 b = *(const f32x4*)&bias[col];
  f32x4 ad = *(const f32x4*)&addend[(size_t)i * 4];
  f32x4 r = s + b + ad;
  *(f32x4*)&out[(size_t)i * 4] = r;
}

// ---------------------------------------------------------------------------
// Small layer GEMM (fp32 SIMT, exact), register-prefetched staging:
//  out[M][128] = op(A1@Wl + A2@Wr + bias)
// ---------------------------------------------------------------------------
template <int RELU>
__global__ __launch_bounds__(256) void gemm_layer(const float* __restrict__ A1,
                                                  const float* __restrict__ A2,
                                                  const float* __restrict__ Wl,
                                                  const float* __restrict__ Wr,
                                                  const float* __restrict__ bias,
                                                  float* __restrict__ out) {
  __shared__ float aT[32][33];
  __shared__ float wT[32][128];
  const int t = threadIdx.x;
  const int tx = t & 15, ty = t >> 4;
  const int m0 = blockIdx.x * 32;
  const int arow = t >> 3, ac = t & 7;       // A staging: 32 rows x 8 float4
  const int wrow8 = t >> 5, wc = t & 31;     // W staging: (i*8+wrow8) x 32 float4
  float acc[2][8] = {};

  float4 a_v;
  float4 w_v[4];
  a_v = *(const float4*)&A1[(size_t)(m0 + arow) * 128 + ac * 4];
#pragma unroll
  for (int i = 0; i < 4; ++i)
    w_v[i] = *(const float4*)&Wl[(size_t)(i * 8 + wrow8) * 128 + wc * 4];

  for (int kc = 0; kc < 8; ++kc) {
    __syncthreads();
    aT[arow][ac * 4 + 0] = a_v.x; aT[arow][ac * 4 + 1] = a_v.y;
    aT[arow][ac * 4 + 2] = a_v.z; aT[arow][ac * 4 + 3] = a_v.w;
#pragma unroll
    for (int i = 0; i < 4; ++i) *(float4*)&wT[i * 8 + wrow8][wc * 4] = w_v[i];
    if (kc + 1 < 8) {
      int nk = kc + 1;
      const float* Asrc = (nk < 4) ? A1 : A2;
      const float* Wsrc = (nk < 4) ? Wl : Wr;
      int kb = (nk & 3) * 32;
      a_v = *(const float4*)&Asrc[(size_t)(m0 + arow) * 128 + kb + ac * 4];
#pragma unroll
      for (int i = 0; i < 4; ++i)
        w_v[i] = *(const float4*)&Wsrc[(size_t)(kb + i * 8 + wrow8) * 128 + wc * 4];
    }
    __syncthreads();
#pragma unroll
    for (int k = 0; k < 32; ++k) {
      float a0 = aT[ty * 2 + 0][k], a1 = aT[ty * 2 + 1][k];
      float4 w0 = *(const float4*)&wT[k][tx * 8];
      float4 w1 = *(const float4*)&wT[k][tx * 8 + 4];
      float w[8] = {w0.x, w0.y, w0.z, w0.w, w1.x, w1.y, w1.z, w1.w};
#pragma unroll
      for (int j = 0; j < 8; ++j) {
        acc[0][j] += a0 * w[j];
        acc[1][j] += a1 * w[j];
      }
    }
  }
#pragma unroll
  for (int i = 0; i < 2; ++i) {
    int row = m0 + ty * 2 + i;
    float o[8];
#pragma unroll
    for (int j = 0; j < 8; ++j) {
      float v = acc[i][j] + bias[tx * 8 + j];
      o[j] = RELU ? fmaxf(v, 0.f) : v;
    }
    float4 v0 = {o[0], o[1], o[2], o[3]}, v1 = {o[4], o[5], o[6], o[7]};
    *(float4*)&out[(size_t)row * 128 + tx * 8] = v0;
    *(float4*)&out[(size_t)row * 128 + tx * 8 + 4] = v1;
  }
}

// ---------------------------------------------------------------------------
// CSR mean aggregation: wave per dst node; half-wave per neighbor, float4/lane
// (32 lanes cover the 128-col row). 2 neighbors per step, 2-deep batching.
// ---------------------------------------------------------------------------
__global__ __launch_bounds__(256) void agg_mean(const int* __restrict__ adj,
                                                const int* __restrict__ off,
                                                const float* __restrict__ X,
                                                float* __restrict__ out, int ndst) {
  int w = blockIdx.x * 4 + (threadIdx.x >> 6);
  if (w >= ndst) return;
  int lane = threadIdx.x & 63;
  int h = lane >> 5, c = lane & 31;
  int s0 = off[w], deg = off[w + 1] - s0;
  f32x4 acc0 = {}, acc1 = {};
  for (int base = 0; base < deg; base += 64) {
    int my = base + lane;
    int sv = (my < deg) ? adj[s0 + my] : 0;
    int cnt = min(64, deg - base);
    int jj = 0;
    for (; jj + 4 <= cnt; jj += 4) {
      int n0 = __shfl(sv, jj + h);
      int n1 = __shfl(sv, jj + 2 + h);
      f32x4 f0 = *(const f32x4*)&X[(size_t)n0 * 128 + c * 4];
      f32x4 f1 = *(const f32x4*)&X[(size_t)n1 * 128 + c * 4];
      acc0 += f0; acc1 += f1;
    }
    for (; jj < cnt; jj += 2) {
      int idx = jj + h;
      int n = __shfl(sv, min(idx, cnt - 1));
      if (idx < cnt) {
        f32x4 f = *(const f32x4*)&X[(size_t)n * 128 + c * 4];
        acc0 += f;
      }
    }
  }
  f32x4 acc = acc0 + acc1;
#pragma unroll
  for (int j = 0; j < 4; ++j) acc[j] += __shfl_xor(acc[j], 32);
  if (h == 0) {
    float inv = 1.f / (float)max(deg, 1);
    acc *= inv;
    *(f32x4*)&out[(size_t)w * 128 + c * 4] = acc;
  }
}

// ---------------------------------------------------------------------------
// Edge classifier: 2 edges per wave (half-wave each, float4/lane)
// ---------------------------------------------------------------------------
__global__ __launch_bounds__(256) void edge_dot(const int* __restrict__ ls,
                                                const int* __restrict__ ld,
                                                const float* __restrict__ hc2,
                                                const float* __restrict__ hp2,
                                                float* __restrict__ o, int n) {
  int w = blockIdx.x * 4 + (threadIdx.x >> 6);
  int lane = threadIdx.x & 63;
  int h = lane >> 5, c = lane & 31;
  int e = w * 2 + h;
  if (e >= n) return;
  int s = ls[e], d = ld[e];
  f32x4 a = *(const f32x4*)&hc2[(size_t)s * 128 + c * 4];
  f32x4 b = *(const f32x4*)&hp2[(size_t)d * 128 + c * 4];
  float p = a[0] * b[0] + a[1] * b[1] + a[2] * b[2] + a[3] * b[3];
#pragma unroll
  for (int m = 16; m; m >>= 1) p += __shfl_xor(p, m);
  if (c == 0) o[e] = p;
}

// ---------------------------------------------------------------------------
extern "C" void kernel_launch(void* const* d_in, const int* in_sizes, int n_in,
                              void* d_out, int out_size, void* d_ws, size_t ws_size,
                              hipStream_t stream) {
  const float* x_c    = (const float*)d_in[0];
  const float* x_p    = (const float*)d_in[1];
  const float* Wc     = (const float*)d_in[2];
  const float* bc     = (const float*)d_in[3];
  const float* Wp     = (const float*)d_in[4];
  const float* bp     = (const float*)d_in[5];
  const float* emb_c  = (const float*)d_in[6];
  const float* emb_p  = (const float*)d_in[7];
  const float* W1ep_l = (const float*)d_in[8];
  const float* b1ep   = (const float*)d_in[9];
  const float* W1ep_r = (const float*)d_in[10];
  const float* W1pc_l = (const float*)d_in[11];
  const float* b1pc   = (const float*)d_in[12];
  const float* W1pc_r = (const float*)d_in[13];
  const float* W2ep_l = (const float*)d_in[14];
  const float* b2ep   = (const float*)d_in[15];
  const float* W2ep_r = (const float*)d_in[16];
  const float* W2pc_l = (const float*)d_in[17];
  const float* b2pc   = (const float*)d_in[18];
  const float* W2pc_r = (const float*)d_in[19];
  const int* e_src    = (const int*)d_in[22];
  const int* e_dst    = (const int*)d_in[23];
  const int* l_src    = (const int*)d_in[24];
  const int* l_dst    = (const int*)d_in[25];

  size_t off = 0;
  auto alloc = [&](size_t bytes) -> void* {
    void* p = (char*)d_ws + off;
    off += (bytes + 255) & ~(size_t)255;
    return p;
  };
  float* xc    = (float*)alloc((size_t)NCn * Hn * 4);
  float* xp    = (float*)alloc((size_t)NPn * Hn * 4);
  float* aggP  = (float*)alloc((size_t)NPn * Hn * 4);
  float* aggC  = (float*)alloc((size_t)NCn * Hn * 4);
  float* hp    = (float*)alloc((size_t)NPn * Hn * 4);
  float* hc    = (float*)alloc((size_t)NCn * Hn * 4);
  float* hp2   = (float*)alloc((size_t)NPn * Hn * 4);
  float* hc2   = (float*)alloc((size_t)NCn * Hn * 4);
  u16*   WcT   = (u16*)alloc((size_t)Hn * NCn * 2);
  u16*   WpT   = (u16*)alloc((size_t)Hn * NPn * 2);
  float* partP = (float*)alloc((size_t)8 * NPn * Hn * 4);   // 32 MB
  float* partC = (float*)alloc((size_t)4 * NCn * Hn * 4);   // 8 MB
  int*   adjP  = (int*)alloc((size_t)En * 4);
  int*   adjC  = (int*)alloc((size_t)En * 4);
  int*   offP  = (int*)alloc((size_t)(NPn + 1) * 4);
  int*   offC  = (int*)alloc((size_t)(NCn + 1) * 4);
  int*   curP  = (int*)alloc((size_t)NPn * 4);
  int*   curC  = (int*)alloc((size_t)NCn * 4);
  int*   cnts  = (int*)alloc((size_t)(NPn + NCn) * 4);
  int*   cntP  = cnts;
  int*   cntC  = cnts + NPn;

  hipMemsetAsync(cnts, 0, (size_t)(NPn + NCn) * 4, stream);

  wtrans<<<(128 * (NCn >> 3) + 255) / 256, 256, 0, stream>>>(Wc, WcT, NCn);
  wtrans<<<(128 * (NPn >> 3) + 255) / 256, 256, 0, stream>>>(Wp, WpT, NPn);

  count_deg<<<(En + 255) / 256, 256, 0, stream>>>(e_src, e_dst, cntC, cntP);
  scan_excl<<<1, 256, 0, stream>>>(cntP, offP, curP, NPn);
  scan_excl<<<1, 256, 0, stream>>>(cntC, offC, curC, NCn);
  fill_adj<<<(En + 255) / 256, 256, 0, stream>>>(e_src, e_dst, curC, curP, adjC, adjP);

  gemm_big_sk<<<dim3(NCn / 32, 4), 256, 0, stream>>>(x_c, WcT, partC, NCn, NCn / 4);
  gemm_big_sk<<<dim3(NPn / 32, 8), 256, 0, stream>>>(x_p, WpT, partP, NPn, NPn / 8);
  gemm_combine<<<(NCn * 32 + 255) / 256, 256, 0, stream>>>(partC, bc, emb_c, xc, NCn, 4);
  gemm_combine<<<(NPn * 32 + 255) / 256, 256, 0, stream>>>(partP, bp, emb_p, xp, NPn, 8);

  agg_mean<<<NPn / 4, 256, 0, stream>>>(adjP, offP, xc, aggP, NPn);
  agg_mean<<<NCn / 4, 256, 0, stream>>>(adjC, offC, xp, aggC, NCn);
  gemm_layer<1><<<NPn / 32, 256, 0, stream>>>(aggP, xp, W1ep_l, W1ep_r, b1ep, hp);
  gemm_layer<1><<<NCn / 32, 256, 0, stream>>>(aggC, xc, W1pc_l, W1pc_r, b1pc, hc);

  agg_mean<<<NPn / 4, 256, 0, stream>>>(adjP, offP, hc, aggP, NPn);
  agg_mean<<<NCn / 4, 256, 0, stream>>>(adjC, offC, hp, aggC, NCn);
  gemm_layer<0><<<NPn / 32, 256, 0, stream>>>(aggP, hp, W2ep_l, W2ep_r, b2ep, hp2);
  gemm_layer<0><<<NCn / 32, 256, 0, stream>>>(aggC, hc, W2pc_l, W2pc_r, b2pc, hc2);

  edge_dot<<<(ELn + 7) / 8, 256, 0, stream>>>(l_src, l_dst, hc2, hp2, (float*)d_out, ELn);
}

// Round 3
// 882.936 us; speedup vs baseline: 1.1931x; 1.1931x over previous
//
#include <hip/hip_runtime.h>
#include <stdint.h>

#define NCn 4096
#define NPn 8192
#define Hn  128
#define En  500000
#define ELn 500000

typedef unsigned short u16;
using f32x4  = __attribute__((ext_vector_type(4))) float;
using bf16x8 = __attribute__((ext_vector_type(8))) short;

__device__ inline u16 f2bf(float f) {
  union { float f; uint32_t u; } v; v.f = f;
  uint32_t r = v.u + 0x7fffu + ((v.u >> 16) & 1u);   // RNE
  return (u16)(r >> 16);
}

// ---------------------------------------------------------------------------
// Weight transpose+convert: W[K][128] fp32 -> WT[128][K] bf16
// LDS-tiled: coalesced 128B row-segment loads, coalesced 16B/lane stores.
// Tile = 64k x 32n per block. grid = (K/64, 4)
// ---------------------------------------------------------------------------
__global__ __launch_bounds__(256) void wtrans(const float* __restrict__ W,
                                              u16* __restrict__ WT, int K) {
  __shared__ float sh[64][33];
  const int k0 = blockIdx.x * 64, n0 = blockIdx.y * 32;
  const int t = threadIdx.x;
  {
    int r = t >> 3, c4 = t & 7;
#pragma unroll
    for (int p = 0; p < 2; ++p) {
      int row = p * 32 + r;
      float4 v = *(const float4*)&W[(size_t)(k0 + row) * 128 + n0 + c4 * 4];
      sh[row][c4 * 4 + 0] = v.x; sh[row][c4 * 4 + 1] = v.y;
      sh[row][c4 * 4 + 2] = v.z; sh[row][c4 * 4 + 3] = v.w;
    }
  }
  __syncthreads();
  int n = t >> 3, kq = t & 7;
  u16 pk[8];
#pragma unroll
  for (int j = 0; j < 8; ++j) pk[j] = f2bf(sh[kq * 8 + j][n]);
  uint4 o;
  o.x = (uint32_t)pk[0] | ((uint32_t)pk[1] << 16);
  o.y = (uint32_t)pk[2] | ((uint32_t)pk[3] << 16);
  o.z = (uint32_t)pk[4] | ((uint32_t)pk[5] << 16);
  o.w = (uint32_t)pk[6] | ((uint32_t)pk[7] << 16);
  *(uint4*)&WT[(size_t)(n0 + n) * K + k0 + kq * 8] = o;
}

// ---------------------------------------------------------------------------
// CSR build: count -> exclusive scan -> fill
// ---------------------------------------------------------------------------
__global__ __launch_bounds__(256) void count_deg(const int* __restrict__ esrc,
                                                 const int* __restrict__ edst,
                                                 int* __restrict__ cntC,
                                                 int* __restrict__ cntP) {
  int i = blockIdx.x * 256 + threadIdx.x;
  if (i >= En) return;
  atomicAdd(&cntP[edst[i]], 1);
  atomicAdd(&cntC[esrc[i]], 1);
}

__global__ __launch_bounds__(256) void scan_excl(const int* __restrict__ cnt,
                                                 int* __restrict__ off,
                                                 int* __restrict__ cur, int n) {
  __shared__ int sh[257];
  int t = threadIdx.x;
  int chunk = n >> 8;
  int base = t * chunk;
  int s = 0;
  for (int i = 0; i < chunk; ++i) s += cnt[base + i];
  sh[t] = s;
  __syncthreads();
  if (t == 0) {
    int run = 0;
    for (int i = 0; i < 256; ++i) { int v = sh[i]; sh[i] = run; run += v; }
    sh[256] = run;
  }
  __syncthreads();
  int p = sh[t];
  for (int i = 0; i < chunk; ++i) {
    off[base + i] = p; cur[base + i] = p; p += cnt[base + i];
  }
  if (t == 255) off[n] = sh[256];
}

__global__ __launch_bounds__(256) void fill_adj(const int* __restrict__ esrc,
                                                const int* __restrict__ edst,
                                                int* __restrict__ curC,
                                                int* __restrict__ curP,
                                                int* __restrict__ adjC,
                                                int* __restrict__ adjP) {
  int i = blockIdx.x * 256 + threadIdx.x;
  if (i >= En) return;
  int s = esrc[i], d = edst[i];
  int p = atomicAdd(&curP[d], 1);
  adjP[p] = s;
  int q = atomicAdd(&curC[s], 1);
  adjC[q] = d;
}

// ---------------------------------------------------------------------------
// Split-K big projection GEMM v3: BM=64, BN=128, BK=64.
// A: fp32 global -> regs -> bf16 LDS (XOR-swizzled), 1-iter reg prefetch.
// B: NO LDS — per-wave MFMA fragments loaded directly from L2-resident BT,
//    1-iter reg prefetch. 16 MFMA + 8 ds_read of cover per 8 global loads.
// K-loop 2x-unrolled with named register sets (static indexing only).
// ---------------------------------------------------------------------------
__global__ __launch_bounds__(256) void gemm_big_sk(const float* __restrict__ A,
                                                   const u16* __restrict__ BT,
                                                   float* __restrict__ part,
                                                   int K, int Kc) {
  __shared__ __align__(16) u16 aL[64 * 64];    // 8 KB, [row][k] swizzled
  const int t = threadIdx.x;
  const int wid = t >> 6, lane = t & 63;
  const int ln15 = lane & 15, lhi = lane >> 4;
  const int m0 = blockIdx.x * 64;
  const int kb0 = blockIdx.y * Kc;
  const int nIter = Kc >> 6;                   // always even (>= 16)
  const size_t M128 = (size_t)gridDim.x * 64 * 128;

  f32x4 acc[4][2] = {};

  // A staging: thread t covers row=t>>2 (0..63), 16 floats at cols (t&3)*16
  const int arow = t >> 2, acq = t & 3;
  const float* Ap = &A[(size_t)(m0 + arow) * K + kb0 + acq * 16];
  // B frags: col n = wid*32 + ni*16 + ln15; k = it*64 + ks*32 + lhi*8
  const u16* Bp = &BT[(size_t)(wid * 32 + ln15) * K + kb0 + lhi * 8];
  const size_t BniStride = (size_t)16 * K;

#define LOAD_A(dst, koff)                                                      \
  { _Pragma("unroll") for (int i = 0; i < 4; ++i)                              \
      dst[i] = *(const float4*)(Ap + (koff) + i * 4); }
#define LOAD_B(dst, koff)                                                      \
  { _Pragma("unroll") for (int ni = 0; ni < 2; ++ni)                           \
    _Pragma("unroll") for (int ks = 0; ks < 2; ++ks)                           \
      dst[ni][ks] = *(const bf16x8*)(Bp + ni * BniStride + (koff) + ks * 32); }
#define STORE_A_LDS(src)                                                       \
  { u16 pk[16];                                                                \
    _Pragma("unroll") for (int i = 0; i < 4; ++i) {                            \
      pk[i*4+0] = f2bf(src[i].x); pk[i*4+1] = f2bf(src[i].y);                  \
      pk[i*4+2] = f2bf(src[i].z); pk[i*4+3] = f2bf(src[i].w); }                \
    uint4 w0, w1;                                                              \
    w0.x = (uint32_t)pk[0] | ((uint32_t)pk[1] << 16);                          \
    w0.y = (uint32_t)pk[2] | ((uint32_t)pk[3] << 16);                          \
    w0.z = (uint32_t)pk[4] | ((uint32_t)pk[5] << 16);                          \
    w0.w = (uint32_t)pk[6] | ((uint32_t)pk[7] << 16);                          \
    w1.x = (uint32_t)pk[8] | ((uint32_t)pk[9] << 16);                          \
    w1.y = (uint32_t)pk[10] | ((uint32_t)pk[11] << 16);                        \
    w1.z = (uint32_t)pk[12] | ((uint32_t)pk[13] << 16);                        \
    w1.w = (uint32_t)pk[14] | ((uint32_t)pk[15] << 16);                        \
    int sb = arow * 128;                                                       \
    int sw = (arow & 7) << 4;                                                  \
    *(uint4*)((char*)aL + sb + ((acq * 32) ^ sw)) = w0;                        \
    *(uint4*)((char*)aL + sb + ((acq * 32 + 16) ^ sw)) = w1; }
#define COMPUTE(bset)                                                          \
  { _Pragma("unroll") for (int ks = 0; ks < 2; ++ks) {                         \
      bf16x8 afr[4];                                                           \
      _Pragma("unroll") for (int mi = 0; mi < 4; ++mi) {                       \
        int r = mi * 16 + ln15;                                                \
        afr[mi] = *(const bf16x8*)((const char*)aL + r * 128 +                 \
                    ((ks * 64 + lhi * 16) ^ ((r & 7) << 4)));                  \
      }                                                                        \
      _Pragma("unroll") for (int mi = 0; mi < 4; ++mi)                         \
      _Pragma("unroll") for (int ni = 0; ni < 2; ++ni)                         \
        acc[mi][ni] = __builtin_amdgcn_mfma_f32_16x16x32_bf16(                 \
            afr[mi], bset[ni][ks], acc[mi][ni], 0, 0, 0);                      \
    } }

  float4 avA[4], avB[4];
  bf16x8 bvA[2][2], bvB[2][2];
  LOAD_A(avA, 0)
  LOAD_B(bvA, 0)

  for (int it = 0; it < nIter; it += 2) {
    // ---- even: consume set A, prefetch set B (it+1) ----
    __syncthreads();
    STORE_A_LDS(avA)
    {
      int ko = (it + 1) * 64;
      LOAD_A(avB, ko)
      LOAD_B(bvB, ko)
    }
    __syncthreads();
    COMPUTE(bvA)
    // ---- odd: consume set B, prefetch set A (it+2) ----
    __syncthreads();
    STORE_A_LDS(avB)
    if (it + 2 < nIter) {
      int ko = (it + 2) * 64;
      LOAD_A(avA, ko)
      LOAD_B(bvA, ko)
    }
    __syncthreads();
    COMPUTE(bvB)
  }

  // ---- write fp32 partial ----
  float* P = part + (size_t)blockIdx.y * M128;
#pragma unroll
  for (int mi = 0; mi < 4; ++mi) {
#pragma unroll
    for (int ni = 0; ni < 2; ++ni) {
      int col = wid * 32 + ni * 16 + ln15;
#pragma unroll
      for (int r = 0; r < 4; ++r) {
        int row = m0 + mi * 16 + lhi * 4 + r;
        P[(size_t)row * 128 + col] = acc[mi][ni][r];
      }
    }
  }
#undef LOAD_A
#undef LOAD_B
#undef STORE_A_LDS
#undef COMPUTE
}

// Combine split-K partials: out = sum_c part[c] + bias + addend
__global__ __launch_bounds__(256) void gemm_combine(const float* __restrict__ part,
                                                    const float* __restrict__ bias,
                                                    const float* __restrict__ addend,
                                                    float* __restrict__ out,
                                                    int M, int SK) {
  int i = blockIdx.x * 256 + threadIdx.x;   // float4 index
  int n4 = M * 32;
  if (i >= n4) return;
  size_t stride = (size_t)M * 128;
  f32x4 s = {};
  for (int c = 0; c < SK; ++c) s += *(const f32x4*)&part[c * stride + (size_t)i * 4];
  int col = (i * 4) & 127;
  f32x4 b = *(const f32x4*)&bias[col];
  f32x4 ad = *(const f32x4*)&addend[(size_t)i * 4];
  f32x4 r = s + b + ad;
  *(f32x4*)&out[(size_t)i * 4] = r;
}

// ---------------------------------------------------------------------------
// Small layer GEMM (fp32 SIMT, exact), register-prefetched staging:
//  out[M][128] = op(A1@Wl + A2@Wr + bias)
// ---------------------------------------------------------------------------
template <int RELU>
__global__ __launch_bounds__(256) void gemm_layer(const float* __restrict__ A1,
                                                  const float* __restrict__ A2,
                                                  const float* __restrict__ Wl,
                                                  const float* __restrict__ Wr,
                                                  const float* __restrict__ bias,
                                                  float* __restrict__ out) {
  __shared__ float aT[32][33];
  __shared__ float wT[32][128];
  const int t = threadIdx.x;
  const int tx = t & 15, ty = t >> 4;
  const int m0 = blockIdx.x * 32;
  const int arow = t >> 3, ac = t & 7;
  const int wrow8 = t >> 5, wc = t & 31;
  float acc[2][8] = {};

  float4 a_v;
  float4 w_v[4];
  a_v = *(const float4*)&A1[(size_t)(m0 + arow) * 128 + ac * 4];
#pragma unroll
  for (int i = 0; i < 4; ++i)
    w_v[i] = *(const float4*)&Wl[(size_t)(i * 8 + wrow8) * 128 + wc * 4];

  for (int kc = 0; kc < 8; ++kc) {
    __syncthreads();
    aT[arow][ac * 4 + 0] = a_v.x; aT[arow][ac * 4 + 1] = a_v.y;
    aT[arow][ac * 4 + 2] = a_v.z; aT[arow][ac * 4 + 3] = a_v.w;
#pragma unroll
    for (int i = 0; i < 4; ++i) *(float4*)&wT[i * 8 + wrow8][wc * 4] = w_v[i];
    if (kc + 1 < 8) {
      int nk = kc + 1;
      const float* Asrc = (nk < 4) ? A1 : A2;
      const float* Wsrc = (nk < 4) ? Wl : Wr;
      int kb = (nk & 3) * 32;
      a_v = *(const float4*)&Asrc[(size_t)(m0 + arow) * 128 + kb + ac * 4];
#pragma unroll
      for (int i = 0; i < 4; ++i)
        w_v[i] = *(const float4*)&Wsrc[(size_t)(kb + i * 8 + wrow8) * 128 + wc * 4];
    }
    __syncthreads();
#pragma unroll
    for (int k = 0; k < 32; ++k) {
      float a0 = aT[ty * 2 + 0][k], a1 = aT[ty * 2 + 1][k];
      float4 w0 = *(const float4*)&wT[k][tx * 8];
      float4 w1 = *(const float4*)&wT[k][tx * 8 + 4];
      float w[8] = {w0.x, w0.y, w0.z, w0.w, w1.x, w1.y, w1.z, w1.w};
#pragma unroll
      for (int j = 0; j < 8; ++j) {
        acc[0][j] += a0 * w[j];
        acc[1][j] += a1 * w[j];
      }
    }
  }
#pragma unroll
  for (int i = 0; i < 2; ++i) {
    int row = m0 + ty * 2 + i;
    float o[8];
#pragma unroll
    for (int j = 0; j < 8; ++j) {
      float v = acc[i][j] + bias[tx * 8 + j];
      o[j] = RELU ? fmaxf(v, 0.f) : v;
    }
    float4 v0 = {o[0], o[1], o[2], o[3]}, v1 = {o[4], o[5], o[6], o[7]};
    *(float4*)&out[(size_t)row * 128 + tx * 8] = v0;
    *(float4*)&out[(size_t)row * 128 + tx * 8 + 4] = v1;
  }
}

// ---------------------------------------------------------------------------
// CSR mean aggregation: wave per dst node; half-wave per neighbor, float4/lane
// ---------------------------------------------------------------------------
__global__ __launch_bounds__(256) void agg_mean(const int* __restrict__ adj,
                                                const int* __restrict__ off,
                                                const float* __restrict__ X,
                                                float* __restrict__ out, int ndst) {
  int w = blockIdx.x * 4 + (threadIdx.x >> 6);
  if (w >= ndst) return;
  int lane = threadIdx.x & 63;
  int h = lane >> 5, c = lane & 31;
  int s0 = off[w], deg = off[w + 1] - s0;
  f32x4 acc0 = {}, acc1 = {};
  for (int base = 0; base < deg; base += 64) {
    int my = base + lane;
    int sv = (my < deg) ? adj[s0 + my] : 0;
    int cnt = min(64, deg - base);
    int jj = 0;
    for (; jj + 4 <= cnt; jj += 4) {
      int n0 = __shfl(sv, jj + h);
      int n1 = __shfl(sv, jj + 2 + h);
      f32x4 f0 = *(const f32x4*)&X[(size_t)n0 * 128 + c * 4];
      f32x4 f1 = *(const f32x4*)&X[(size_t)n1 * 128 + c * 4];
      acc0 += f0; acc1 += f1;
    }
    for (; jj < cnt; jj += 2) {
      int idx = jj + h;
      int n = __shfl(sv, min(idx, cnt - 1));
      if (idx < cnt) {
        f32x4 f = *(const f32x4*)&X[(size_t)n * 128 + c * 4];
        acc0 += f;
      }
    }
  }
  f32x4 acc = acc0 + acc1;
#pragma unroll
  for (int j = 0; j < 4; ++j) acc[j] += __shfl_xor(acc[j], 32);
  if (h == 0) {
    float inv = 1.f / (float)max(deg, 1);
    acc *= inv;
    *(f32x4*)&out[(size_t)w * 128 + c * 4] = acc;
  }
}

// ---------------------------------------------------------------------------
// Edge classifier: 2 edges per wave (half-wave each, float4/lane)
// ---------------------------------------------------------------------------
__global__ __launch_bounds__(256) void edge_dot(const int* __restrict__ ls,
                                                const int* __restrict__ ld,
                                                const float* __restrict__ hc2,
                                                const float* __restrict__ hp2,
                                                float* __restrict__ o, int n) {
  int w = blockIdx.x * 4 + (threadIdx.x >> 6);
  int lane = threadIdx.x & 63;
  int h = lane >> 5, c = lane & 31;
  int e = w * 2 + h;
  if (e >= n) return;
  int s = ls[e], d = ld[e];
  f32x4 a = *(const f32x4*)&hc2[(size_t)s * 128 + c * 4];
  f32x4 b = *(const f32x4*)&hp2[(size_t)d * 128 + c * 4];
  float p = a[0] * b[0] + a[1] * b[1] + a[2] * b[2] + a[3] * b[3];
#pragma unroll
  for (int m = 16; m; m >>= 1) p += __shfl_xor(p, m);
  if (c == 0) o[e] = p;
}

// ---------------------------------------------------------------------------
extern "C" void kernel_launch(void* const* d_in, const int* in_sizes, int n_in,
                              void* d_out, int out_size, void* d_ws, size_t ws_size,
                              hipStream_t stream) {
  const float* x_c    = (const float*)d_in[0];
  const float* x_p    = (const float*)d_in[1];
  const float* Wc     = (const float*)d_in[2];
  const float* bc     = (const float*)d_in[3];
  const float* Wp     = (const float*)d_in[4];
  const float* bp     = (const float*)d_in[5];
  const float* emb_c  = (const float*)d_in[6];
  const float* emb_p  = (const float*)d_in[7];
  const float* W1ep_l = (const float*)d_in[8];
  const float* b1ep   = (const float*)d_in[9];
  const float* W1ep_r = (const float*)d_in[10];
  const float* W1pc_l = (const float*)d_in[11];
  const float* b1pc   = (const float*)d_in[12];
  const float* W1pc_r = (const float*)d_in[13];
  const float* W2ep_l = (const float*)d_in[14];
  const float* b2ep   = (const float*)d_in[15];
  const float* W2ep_r = (const float*)d_in[16];
  const float* W2pc_l = (const float*)d_in[17];
  const float* b2pc   = (const float*)d_in[18];
  const float* W2pc_r = (const float*)d_in[19];
  const int* e_src    = (const int*)d_in[22];
  const int* e_dst    = (const int*)d_in[23];
  const int* l_src    = (const int*)d_in[24];
  const int* l_dst    = (const int*)d_in[25];

  size_t off = 0;
  auto alloc = [&](size_t bytes) -> void* {
    void* p = (char*)d_ws + off;
    off += (bytes + 255) & ~(size_t)255;
    return p;
  };
  float* xc    = (float*)alloc((size_t)NCn * Hn * 4);
  float* xp    = (float*)alloc((size_t)NPn * Hn * 4);
  float* aggP  = (float*)alloc((size_t)NPn * Hn * 4);
  float* aggC  = (float*)alloc((size_t)NCn * Hn * 4);
  float* hp    = (float*)alloc((size_t)NPn * Hn * 4);
  float* hc    = (float*)alloc((size_t)NCn * Hn * 4);
  float* hp2   = (float*)alloc((size_t)NPn * Hn * 4);
  float* hc2   = (float*)alloc((size_t)NCn * Hn * 4);
  u16*   WcT   = (u16*)alloc((size_t)Hn * NCn * 2);
  u16*   WpT   = (u16*)alloc((size_t)Hn * NPn * 2);
  float* partP = (float*)alloc((size_t)8 * NPn * Hn * 4);   // 32 MB
  float* partC = (float*)alloc((size_t)4 * NCn * Hn * 4);   // 8 MB
  int*   adjP  = (int*)alloc((size_t)En * 4);
  int*   adjC  = (int*)alloc((size_t)En * 4);
  int*   offP  = (int*)alloc((size_t)(NPn + 1) * 4);
  int*   offC  = (int*)alloc((size_t)(NCn + 1) * 4);
  int*   curP  = (int*)alloc((size_t)NPn * 4);
  int*   curC  = (int*)alloc((size_t)NCn * 4);
  int*   cnts  = (int*)alloc((size_t)(NPn + NCn) * 4);
  int*   cntP  = cnts;
  int*   cntC  = cnts + NPn;

  hipMemsetAsync(cnts, 0, (size_t)(NPn + NCn) * 4, stream);

  wtrans<<<dim3(NCn / 64, 4), 256, 0, stream>>>(Wc, WcT, NCn);
  wtrans<<<dim3(NPn / 64, 4), 256, 0, stream>>>(Wp, WpT, NPn);

  count_deg<<<(En + 255) / 256, 256, 0, stream>>>(e_src, e_dst, cntC, cntP);
  scan_excl<<<1, 256, 0, stream>>>(cntP, offP, curP, NPn);
  scan_excl<<<1, 256, 0, stream>>>(cntC, offC, curC, NCn);
  fill_adj<<<(En + 255) / 256, 256, 0, stream>>>(e_src, e_dst, curC, curP, adjC, adjP);

  gemm_big_sk<<<dim3(NCn / 64, 4), 256, 0, stream>>>(x_c, WcT, partC, NCn, NCn / 4);
  gemm_big_sk<<<dim3(NPn / 64, 8), 256, 0, stream>>>(x_p, WpT, partP, NPn, NPn / 8);
  gemm_combine<<<(NCn * 32 + 255) / 256, 256, 0, stream>>>(partC, bc, emb_c, xc, NCn, 4);
  gemm_combine<<<(NPn * 32 + 255) / 256, 256, 0, stream>>>(partP, bp, emb_p, xp, NPn, 8);

  agg_mean<<<NPn / 4, 256, 0, stream>>>(adjP, offP, xc, aggP, NPn);
  agg_mean<<<NCn / 4, 256, 0, stream>>>(adjC, offC, xp, aggC, NCn);
  gemm_layer<1><<<NPn / 32, 256, 0, stream>>>(aggP, xp, W1ep_l, W1ep_r, b1ep, hp);
  gemm_layer<1><<<NCn / 32, 256, 0, stream>>>(aggC, xc, W1pc_l, W1pc_r, b1pc, hc);

  agg_mean<<<NPn / 4, 256, 0, stream>>>(adjP, offP, hc, aggP, NPn);
  agg_mean<<<NCn / 4, 256, 0, stream>>>(adjC, offC, hp, aggC, NCn);
  gemm_layer<0><<<NPn / 32, 256, 0, stream>>>(aggP, hp, W2ep_l, W2ep_r, b2ep, hp2);
  gemm_layer<0><<<NCn / 32, 256, 0, stream>>>(aggC, hc, W2pc_l, W2pc_r, b2pc, hc2);

  edge_dot<<<(ELn + 7) / 8, 256, 0, stream>>>(l_src, l_dst, hc2, hp2, (float*)d_out, ELn);
}

// Round 9
// 842.394 us; speedup vs baseline: 1.2505x; 1.0481x over previous
//
#include <hip/hip_runtime.h>
#include <stdint.h>

#define NCn 4096
#define NPn 8192
#define Hn  128
#define En  500000
#define ELn 500000

typedef unsigned short u16;
using f32x4  = __attribute__((ext_vector_type(4))) float;
using bf16x8 = __attribute__((ext_vector_type(8))) short;

__device__ inline u16 f2bf(float f) {
  union { float f; uint32_t u; } v; v.f = f;
  uint32_t r = v.u + 0x7fffu + ((v.u >> 16) & 1u);   // RNE
  return (u16)(r >> 16);
}
__device__ inline float bfu(uint32_t u) {            // bf16 bits (low 16) -> f32
  union { uint32_t x; float f; } z; z.x = u << 16; return z.f;
}

// ---------------------------------------------------------------------------
// Weight transpose+convert: W[K][128] fp32 -> WT[128][K] bf16 (LDS-tiled)
// ---------------------------------------------------------------------------
__global__ __launch_bounds__(256) void wtrans(const float* __restrict__ W,
                                              u16* __restrict__ WT, int K) {
  __shared__ float sh[64][33];
  const int k0 = blockIdx.x * 64, n0 = blockIdx.y * 32;
  const int t = threadIdx.x;
  {
    int r = t >> 3, c4 = t & 7;
#pragma unroll
    for (int p = 0; p < 2; ++p) {
      int row = p * 32 + r;
      float4 v = *(const float4*)&W[(size_t)(k0 + row) * 128 + n0 + c4 * 4];
      sh[row][c4 * 4 + 0] = v.x; sh[row][c4 * 4 + 1] = v.y;
      sh[row][c4 * 4 + 2] = v.z; sh[row][c4 * 4 + 3] = v.w;
    }
  }
  __syncthreads();
  int n = t >> 3, kq = t & 7;
  u16 pk[8];
#pragma unroll
  for (int j = 0; j < 8; ++j) pk[j] = f2bf(sh[kq * 8 + j][n]);
  uint4 o;
  o.x = (uint32_t)pk[0] | ((uint32_t)pk[1] << 16);
  o.y = (uint32_t)pk[2] | ((uint32_t)pk[3] << 16);
  o.z = (uint32_t)pk[4] | ((uint32_t)pk[5] << 16);
  o.w = (uint32_t)pk[6] | ((uint32_t)pk[7] << 16);
  *(uint4*)&WT[(size_t)(n0 + n) * K + k0 + kq * 8] = o;
}

// ---------------------------------------------------------------------------
// CSR build: count -> exclusive scan (merged, 2 blocks) -> fill
// ---------------------------------------------------------------------------
__global__ __launch_bounds__(256) void count_deg(const int* __restrict__ esrc,
                                                 const int* __restrict__ edst,
                                                 int* __restrict__ cntC,
                                                 int* __restrict__ cntP) {
  int i = blockIdx.x * 256 + threadIdx.x;
  if (i >= En) return;
  atomicAdd(&cntP[edst[i]], 1);
  atomicAdd(&cntC[esrc[i]], 1);
}

__global__ __launch_bounds__(256) void scan2(const int* __restrict__ cntP,
                                             const int* __restrict__ cntC,
                                             int* __restrict__ offP,
                                             int* __restrict__ offC,
                                             int* __restrict__ curP,
                                             int* __restrict__ curC) {
  __shared__ int sh[257];
  const int* cnt; int* off; int* cur; int n;
  if (blockIdx.x == 0) { cnt = cntP; off = offP; cur = curP; n = NPn; }
  else                 { cnt = cntC; off = offC; cur = curC; n = NCn; }
  int t = threadIdx.x;
  int chunk = n >> 8;
  int base = t * chunk;
  int s = 0;
#pragma unroll 4
  for (int i = 0; i < chunk; ++i) s += cnt[base + i];
  sh[t] = s;
  __syncthreads();
  if (t == 0) {
    int run = 0;
    for (int i = 0; i < 256; ++i) { int v = sh[i]; sh[i] = run; run += v; }
    sh[256] = run;
  }
  __syncthreads();
  int p = sh[t];
  for (int i = 0; i < chunk; ++i) {
    off[base + i] = p; cur[base + i] = p; p += cnt[base + i];
  }
  if (t == 255) off[n] = sh[256];
}

__global__ __launch_bounds__(256) void fill_adj(const int* __restrict__ esrc,
                                                const int* __restrict__ edst,
                                                int* __restrict__ curC,
                                                int* __restrict__ curP,
                                                int* __restrict__ adjC,
                                                int* __restrict__ adjP) {
  int i = blockIdx.x * 256 + threadIdx.x;
  if (i >= En) return;
  int s = esrc[i], d = edst[i];
  int p = atomicAdd(&curP[d], 1);
  adjP[p] = s;
  int q = atomicAdd(&curC[s], 1);
  adjC[q] = d;
}

// ---------------------------------------------------------------------------
// Split-K big projection GEMM v3: BM=64, BN=128, BK=64.
// A: fp32 global -> regs -> bf16 LDS (XOR-swizzled), 1-iter reg prefetch.
// B: NO LDS — per-wave MFMA fragments loaded directly from L2-resident BT.
// ---------------------------------------------------------------------------
__global__ __launch_bounds__(256) void gemm_big_sk(const float* __restrict__ A,
                                                   const u16* __restrict__ BT,
                                                   float* __restrict__ part,
                                                   int K, int Kc) {
  __shared__ __align__(16) u16 aL[64 * 64];
  const int t = threadIdx.x;
  const int wid = t >> 6, lane = t & 63;
  const int ln15 = lane & 15, lhi = lane >> 4;
  const int m0 = blockIdx.x * 64;
  const int kb0 = blockIdx.y * Kc;
  const int nIter = Kc >> 6;
  const size_t M128 = (size_t)gridDim.x * 64 * 128;

  f32x4 acc[4][2] = {};

  const int arow = t >> 2, acq = t & 3;
  const float* Ap = &A[(size_t)(m0 + arow) * K + kb0 + acq * 16];
  const u16* Bp = &BT[(size_t)(wid * 32 + ln15) * K + kb0 + lhi * 8];
  const size_t BniStride = (size_t)16 * K;

#define LOAD_A(dst, koff)                                                      \
  { _Pragma("unroll") for (int i = 0; i < 4; ++i)                              \
      dst[i] = *(const float4*)(Ap + (koff) + i * 4); }
#define LOAD_B(dst, koff)                                                      \
  { _Pragma("unroll") for (int ni = 0; ni < 2; ++ni)                           \
    _Pragma("unroll") for (int ks = 0; ks < 2; ++ks)                           \
      dst[ni][ks] = *(const bf16x8*)(Bp + ni * BniStride + (koff) + ks * 32); }
#define STORE_A_LDS(src)                                                       \
  { u16 pk[16];                                                                \
    _Pragma("unroll") for (int i = 0; i < 4; ++i) {                            \
      pk[i*4+0] = f2bf(src[i].x); pk[i*4+1] = f2bf(src[i].y);                  \
      pk[i*4+2] = f2bf(src[i].z); pk[i*4+3] = f2bf(src[i].w); }                \
    uint4 w0, w1;                                                              \
    w0.x = (uint32_t)pk[0] | ((uint32_t)pk[1] << 16);                          \
    w0.y = (uint32_t)pk[2] | ((uint32_t)pk[3] << 16);                          \
    w0.z = (uint32_t)pk[4] | ((uint32_t)pk[5] << 16);                          \
    w0.w = (uint32_t)pk[6] | ((uint32_t)pk[7] << 16);                          \
    w1.x = (uint32_t)pk[8] | ((uint32_t)pk[9] << 16);                          \
    w1.y = (uint32_t)pk[10] | ((uint32_t)pk[11] << 16);                        \
    w1.z = (uint32_t)pk[12] | ((uint32_t)pk[13] << 16);                        \
    w1.w = (uint32_t)pk[14] | ((uint32_t)pk[15] << 16);                        \
    int sb = arow * 128;                                                       \
    int sw = (arow & 7) << 4;                                                  \
    *(uint4*)((char*)aL + sb + ((acq * 32) ^ sw)) = w0;                        \
    *(uint4*)((char*)aL + sb + ((acq * 32 + 16) ^ sw)) = w1; }
#define COMPUTE(bset)                                                          \
  { _Pragma("unroll") for (int ks = 0; ks < 2; ++ks) {                         \
      bf16x8 afr[4];                                                           \
      _Pragma("unroll") for (int mi = 0; mi < 4; ++mi) {                       \
        int r = mi * 16 + ln15;                                                \
        afr[mi] = *(const bf16x8*)((const char*)aL + r * 128 +                 \
                    ((ks * 64 + lhi * 16) ^ ((r & 7) << 4)));                  \
      }                                                                        \
      _Pragma("unroll") for (int mi = 0; mi < 4; ++mi)                         \
      _Pragma("unroll") for (int ni = 0; ni < 2; ++ni)                         \
        acc[mi][ni] = __builtin_amdgcn_mfma_f32_16x16x32_bf16(                 \
            afr[mi], bset[ni][ks], acc[mi][ni], 0, 0, 0);                      \
    } }

  float4 avA[4], avB[4];
  bf16x8 bvA[2][2], bvB[2][2];
  LOAD_A(avA, 0)
  LOAD_B(bvA, 0)

  for (int it = 0; it < nIter; it += 2) {
    __syncthreads();
    STORE_A_LDS(avA)
    {
      int ko = (it + 1) * 64;
      LOAD_A(avB, ko)
      LOAD_B(bvB, ko)
    }
    __syncthreads();
    COMPUTE(bvA)
    __syncthreads();
    STORE_A_LDS(avB)
    if (it + 2 < nIter) {
      int ko = (it + 2) * 64;
      LOAD_A(avA, ko)
      LOAD_B(bvA, ko)
    }
    __syncthreads();
    COMPUTE(bvB)
  }

  float* P = part + (size_t)blockIdx.y * M128;
#pragma unroll
  for (int mi = 0; mi < 4; ++mi) {
#pragma unroll
    for (int ni = 0; ni < 2; ++ni) {
      int col = wid * 32 + ni * 16 + ln15;
#pragma unroll
      for (int r = 0; r < 4; ++r) {
        int row = m0 + mi * 16 + lhi * 4 + r;
        P[(size_t)row * 128 + col] = acc[mi][ni][r];
      }
    }
  }
#undef LOAD_A
#undef LOAD_B
#undef STORE_A_LDS
#undef COMPUTE
}

// Combine split-K partials: out = sum_c part[c] + bias + addend
// Dual-write: fp32 (for lin_r GEMM input) + bf16 (for aggregation gathers)
__global__ __launch_bounds__(256) void gemm_combine(const float* __restrict__ part,
                                                    const float* __restrict__ bias,
                                                    const float* __restrict__ addend,
                                                    float* __restrict__ out,
                                                    u16* __restrict__ outH,
                                                    int M, int SK) {
  int i = blockIdx.x * 256 + threadIdx.x;
  int n4 = M * 32;
  if (i >= n4) return;
  size_t stride = (size_t)M * 128;
  f32x4 s = {};
  for (int c = 0; c < SK; ++c) s += *(const f32x4*)&part[c * stride + (size_t)i * 4];
  int col = (i * 4) & 127;
  f32x4 b = *(const f32x4*)&bias[col];
  f32x4 ad = *(const f32x4*)&addend[(size_t)i * 4];
  f32x4 r = s + b + ad;
  *(f32x4*)&out[(size_t)i * 4] = r;
  uint2 h;
  h.x = (uint32_t)f2bf(r[0]) | ((uint32_t)f2bf(r[1]) << 16);
  h.y = (uint32_t)f2bf(r[2]) | ((uint32_t)f2bf(r[3]) << 16);
  *(uint2*)&outH[(size_t)i * 4] = h;
}

// ---------------------------------------------------------------------------
// Small layer GEMM (fp32 SIMT, exact), register-prefetched staging.
// Optionally dual-writes a bf16 copy (for next layer's aggregation gathers).
// ---------------------------------------------------------------------------
template <int RELU>
__global__ __launch_bounds__(256) void gemm_layer(const float* __restrict__ A1,
                                                  const float* __restrict__ A2,
                                                  const float* __restrict__ Wl,
                                                  const float* __restrict__ Wr,
                                                  const float* __restrict__ bias,
                                                  float* __restrict__ out,
                                                  u16* __restrict__ outH) {
  __shared__ float aT[32][33];
  __shared__ float wT[32][128];
  const int t = threadIdx.x;
  const int tx = t & 15, ty = t >> 4;
  const int m0 = blockIdx.x * 32;
  const int arow = t >> 3, ac = t & 7;
  const int wrow8 = t >> 5, wc = t & 31;
  float acc[2][8] = {};

  float4 a_v;
  float4 w_v[4];
  a_v = *(const float4*)&A1[(size_t)(m0 + arow) * 128 + ac * 4];
#pragma unroll
  for (int i = 0; i < 4; ++i)
    w_v[i] = *(const float4*)&Wl[(size_t)(i * 8 + wrow8) * 128 + wc * 4];

  for (int kc = 0; kc < 8; ++kc) {
    __syncthreads();
    aT[arow][ac * 4 + 0] = a_v.x; aT[arow][ac * 4 + 1] = a_v.y;
    aT[arow][ac * 4 + 2] = a_v.z; aT[arow][ac * 4 + 3] = a_v.w;
#pragma unroll
    for (int i = 0; i < 4; ++i) *(float4*)&wT[i * 8 + wrow8][wc * 4] = w_v[i];
    if (kc + 1 < 8) {
      int nk = kc + 1;
      const float* Asrc = (nk < 4) ? A1 : A2;
      const float* Wsrc = (nk < 4) ? Wl : Wr;
      int kb = (nk & 3) * 32;
      a_v = *(const float4*)&Asrc[(size_t)(m0 + arow) * 128 + kb + ac * 4];
#pragma unroll
      for (int i = 0; i < 4; ++i)
        w_v[i] = *(const float4*)&Wsrc[(size_t)(kb + i * 8 + wrow8) * 128 + wc * 4];
    }
    __syncthreads();
#pragma unroll
    for (int k = 0; k < 32; ++k) {
      float a0 = aT[ty * 2 + 0][k], a1 = aT[ty * 2 + 1][k];
      float4 w0 = *(const float4*)&wT[k][tx * 8];
      float4 w1 = *(const float4*)&wT[k][tx * 8 + 4];
      float w[8] = {w0.x, w0.y, w0.z, w0.w, w1.x, w1.y, w1.z, w1.w};
#pragma unroll
      for (int j = 0; j < 8; ++j) {
        acc[0][j] += a0 * w[j];
        acc[1][j] += a1 * w[j];
      }
    }
  }
#pragma unroll
  for (int i = 0; i < 2; ++i) {
    int row = m0 + ty * 2 + i;
    float o[8];
#pragma unroll
    for (int j = 0; j < 8; ++j) {
      float v = acc[i][j] + bias[tx * 8 + j];
      o[j] = RELU ? fmaxf(v, 0.f) : v;
    }
    float4 v0 = {o[0], o[1], o[2], o[3]}, v1 = {o[4], o[5], o[6], o[7]};
    *(float4*)&out[(size_t)row * 128 + tx * 8] = v0;
    *(float4*)&out[(size_t)row * 128 + tx * 8 + 4] = v1;
    if (outH) {
      uint4 h;
      h.x = (uint32_t)f2bf(o[0]) | ((uint32_t)f2bf(o[1]) << 16);
      h.y = (uint32_t)f2bf(o[2]) | ((uint32_t)f2bf(o[3]) << 16);
      h.z = (uint32_t)f2bf(o[4]) | ((uint32_t)f2bf(o[5]) << 16);
      h.w = (uint32_t)f2bf(o[6]) | ((uint32_t)f2bf(o[7]) << 16);
      *(uint4*)&outH[(size_t)row * 128 + tx * 8] = h;
    }
  }
}

// ---------------------------------------------------------------------------
// CSR mean aggregation over bf16 features: wave per dst node; quarter-wave
// (16 lanes) per neighbor, 16 B (8 bf16) per lane, fp32 accumulation.
// 2-deep load batching (8 neighbors per wave step).
// ---------------------------------------------------------------------------
__global__ __launch_bounds__(256) void agg_mean_h(const int* __restrict__ adj,
                                                  const int* __restrict__ off,
                                                  const u16* __restrict__ Xh,
                                                  float* __restrict__ out, int ndst) {
  int w = blockIdx.x * 4 + (threadIdx.x >> 6);
  if (w >= ndst) return;
  int lane = threadIdx.x & 63;
  int q = lane >> 4, c = lane & 15;
  int s0 = off[w], deg = off[w + 1] - s0;
  f32x4 acc0 = {}, acc1 = {};
#define ACC8(v)                                                                \
  { acc0[0] += bfu((v).x & 0xffffu); acc0[1] += bfu((v).x >> 16);              \
    acc0[2] += bfu((v).y & 0xffffu); acc0[3] += bfu((v).y >> 16);              \
    acc1[0] += bfu((v).z & 0xffffu); acc1[1] += bfu((v).z >> 16);              \
    acc1[2] += bfu((v).w & 0xffffu); acc1[3] += bfu((v).w >> 16); }
  for (int base = 0; base < deg; base += 64) {
    int my = base + lane;
    int sv = (my < deg) ? adj[s0 + my] : 0;
    int cnt = min(64, deg - base);
    int jj = 0;
    for (; jj + 8 <= cnt; jj += 8) {
      int n0 = __shfl(sv, jj + q);
      int n1 = __shfl(sv, jj + 4 + q);
      uint4 v0 = *(const uint4*)&Xh[(size_t)n0 * 128 + c * 8];
      uint4 v1 = *(const uint4*)&Xh[(size_t)n1 * 128 + c * 8];
      ACC8(v0)
      ACC8(v1)
    }
    for (; jj + 4 <= cnt; jj += 4) {
      int n0 = __shfl(sv, jj + q);
      uint4 v0 = *(const uint4*)&Xh[(size_t)n0 * 128 + c * 8];
      ACC8(v0)
    }
    int r = cnt - jj;
    if (r > 0) {
      int n0 = __shfl(sv, min(jj + q, cnt - 1));
      if (q < r) {
        uint4 v0 = *(const uint4*)&Xh[(size_t)n0 * 128 + c * 8];
        ACC8(v0)
      }
    }
  }
#undef ACC8
#pragma unroll
  for (int j = 0; j < 4; ++j) {
    acc0[j] += __shfl_xor(acc0[j], 16);
    acc0[j] += __shfl_xor(acc0[j], 32);
    acc1[j] += __shfl_xor(acc1[j], 16);
    acc1[j] += __shfl_xor(acc1[j], 32);
  }
  if (q == 0) {
    float inv = 1.f / (float)max(deg, 1);
    acc0 *= inv; acc1 *= inv;
    *(f32x4*)&out[(size_t)w * 128 + c * 8] = acc0;
    *(f32x4*)&out[(size_t)w * 128 + c * 8 + 4] = acc1;
  }
}

// ---------------------------------------------------------------------------
// Edge classifier: 4 edges per wave (quarter-wave each, 8 floats/lane), fp32
// ---------------------------------------------------------------------------
__global__ __launch_bounds__(256) void edge_dot(const int* __restrict__ ls,
                                                const int* __restrict__ ld,
                                                const float* __restrict__ hc2,
                                                const float* __restrict__ hp2,
                                                float* __restrict__ o, int n) {
  int w = blockIdx.x * 4 + (threadIdx.x >> 6);
  int lane = threadIdx.x & 63;
  int q = lane >> 4, c = lane & 15;
  int e = w * 4 + q;
  if (e >= n) return;
  int s = ls[e], d = ld[e];
  const float* pa = &hc2[(size_t)s * 128 + c * 8];
  const float* pb = &hp2[(size_t)d * 128 + c * 8];
  f32x4 a0 = *(const f32x4*)pa, a1 = *(const f32x4*)(pa + 4);
  f32x4 b0 = *(const f32x4*)pb, b1 = *(const f32x4*)(pb + 4);
  f32x4 pv = a0 * b0 + a1 * b1;
  float p = pv[0] + pv[1] + pv[2] + pv[3];
#pragma unroll
  for (int m = 8; m; m >>= 1) p += __shfl_xor(p, m);
  if (c == 0) o[e] = p;
}

// ---------------------------------------------------------------------------
extern "C" void kernel_launch(void* const* d_in, const int* in_sizes, int n_in,
                              void* d_out, int out_size, void* d_ws, size_t ws_size,
                              hipStream_t stream) {
  const float* x_c    = (const float*)d_in[0];
  const float* x_p    = (const float*)d_in[1];
  const float* Wc     = (const float*)d_in[2];
  const float* bc     = (const float*)d_in[3];
  const float* Wp     = (const float*)d_in[4];
  const float* bp     = (const float*)d_in[5];
  const float* emb_c  = (const float*)d_in[6];
  const float* emb_p  = (const float*)d_in[7];
  const float* W1ep_l = (const float*)d_in[8];
  const float* b1ep   = (const float*)d_in[9];
  const float* W1ep_r = (const float*)d_in[10];
  const float* W1pc_l = (const float*)d_in[11];
  const float* b1pc   = (const float*)d_in[12];
  const float* W1pc_r = (const float*)d_in[13];
  const float* W2ep_l = (const float*)d_in[14];
  const float* b2ep   = (const float*)d_in[15];
  const float* W2ep_r = (const float*)d_in[16];
  const float* W2pc_l = (const float*)d_in[17];
  const float* b2pc   = (const float*)d_in[18];
  const float* W2pc_r = (const float*)d_in[19];
  const int* e_src    = (const int*)d_in[22];
  const int* e_dst    = (const int*)d_in[23];
  const int* l_src    = (const int*)d_in[24];
  const int* l_dst    = (const int*)d_in[25];

  size_t off = 0;
  auto alloc = [&](size_t bytes) -> void* {
    void* p = (char*)d_ws + off;
    off += (bytes + 255) & ~(size_t)255;
    return p;
  };
  float* xc    = (float*)alloc((size_t)NCn * Hn * 4);
  float* xp    = (float*)alloc((size_t)NPn * Hn * 4);
  float* aggP  = (float*)alloc((size_t)NPn * Hn * 4);
  float* aggC  = (float*)alloc((size_t)NCn * Hn * 4);
  float* hp    = (float*)alloc((size_t)NPn * Hn * 4);
  float* hc    = (float*)alloc((size_t)NCn * Hn * 4);
  float* hp2   = (float*)alloc((size_t)NPn * Hn * 4);
  float* hc2   = (float*)alloc((size_t)NCn * Hn * 4);
  u16*   xcH   = (u16*)alloc((size_t)NCn * Hn * 2);
  u16*   xpH   = (u16*)alloc((size_t)NPn * Hn * 2);
  u16*   hpH   = (u16*)alloc((size_t)NPn * Hn * 2);
  u16*   hcH   = (u16*)alloc((size_t)NCn * Hn * 2);
  u16*   WcT   = (u16*)alloc((size_t)Hn * NCn * 2);
  u16*   WpT   = (u16*)alloc((size_t)Hn * NPn * 2);
  float* partP = (float*)alloc((size_t)8 * NPn * Hn * 4);
  float* partC = (float*)alloc((size_t)4 * NCn * Hn * 4);
  int*   adjP  = (int*)alloc((size_t)En * 4);
  int*   adjC  = (int*)alloc((size_t)En * 4);
  int*   offP  = (int*)alloc((size_t)(NPn + 1) * 4);
  int*   offC  = (int*)alloc((size_t)(NCn + 1) * 4);
  int*   curP  = (int*)alloc((size_t)NPn * 4);
  int*   curC  = (int*)alloc((size_t)NCn * 4);
  int*   cnts  = (int*)alloc((size_t)(NPn + NCn) * 4);
  int*   cntP  = cnts;
  int*   cntC  = cnts + NPn;

  hipMemsetAsync(cnts, 0, (size_t)(NPn + NCn) * 4, stream);

  // CSR build
  count_deg<<<(En + 255) / 256, 256, 0, stream>>>(e_src, e_dst, cntC, cntP);
  scan2<<<2, 256, 0, stream>>>(cntP, cntC, offP, offC, curP, curC);
  fill_adj<<<(En + 255) / 256, 256, 0, stream>>>(e_src, e_dst, curC, curP, adjC, adjP);

  // input projections
  wtrans<<<dim3(NCn / 64, 4), 256, 0, stream>>>(Wc, WcT, NCn);
  wtrans<<<dim3(NPn / 64, 4), 256, 0, stream>>>(Wp, WpT, NPn);
  gemm_big_sk<<<dim3(NCn / 64, 4), 256, 0, stream>>>(x_c, WcT, partC, NCn, NCn / 4);
  gemm_big_sk<<<dim3(NPn / 64, 8), 256, 0, stream>>>(x_p, WpT, partP, NPn, NPn / 8);
  gemm_combine<<<(NCn * 32 + 255) / 256, 256, 0, stream>>>(partC, bc, emb_c, xc, xcH, NCn, 4);
  gemm_combine<<<(NPn * 32 + 255) / 256, 256, 0, stream>>>(partP, bp, emb_p, xp, xpH, NPn, 8);

  // layer 1 (bf16 gathers, fp32 GEMM; writes bf16 copies for layer-2 gathers)
  agg_mean_h<<<NPn / 4, 256, 0, stream>>>(adjP, offP, xcH, aggP, NPn);
  agg_mean_h<<<NCn / 4, 256, 0, stream>>>(adjC, offC, xpH, aggC, NCn);
  gemm_layer<1><<<NPn / 32, 256, 0, stream>>>(aggP, xp, W1ep_l, W1ep_r, b1ep, hp, hpH);
  gemm_layer<1><<<NCn / 32, 256, 0, stream>>>(aggC, xc, W1pc_l, W1pc_r, b1pc, hc, hcH);

  // layer 2 (bf16 gathers; fp32 outputs only)
  agg_mean_h<<<NPn / 4, 256, 0, stream>>>(adjP, offP, hcH, aggP, NPn);
  agg_mean_h<<<NCn / 4, 256, 0, stream>>>(adjC, offC, hpH, aggC, NCn);
  gemm_layer<0><<<NPn / 32, 256, 0, stream>>>(aggP, hp, W2ep_l, W2ep_r, b2ep, hp2, nullptr);
  gemm_layer<0><<<NCn / 32, 256, 0, stream>>>(aggC, hc, W2pc_l, W2pc_r, b2pc, hc2, nullptr);

  // classifier
  edge_dot<<<(ELn + 15) / 16, 256, 0, stream>>>(l_src, l_dst, hc2, hp2,
                                                (float*)d_out, ELn);
}

// Round 10
// 830.546 us; speedup vs baseline: 1.2684x; 1.0143x over previous
//
#include <hip/hip_runtime.h>
#include <stdint.h>

#define NCn 4096
#define NPn 8192
#define Hn  128
#define En  500000
#define ELn 500000

typedef unsigned short u16;
using f32x4  = __attribute__((ext_vector_type(4))) float;
using bf16x8 = __attribute__((ext_vector_type(8))) short;

__device__ inline u16 f2bf(float f) {
  union { float f; uint32_t u; } v; v.f = f;
  uint32_t r = v.u + 0x7fffu + ((v.u >> 16) & 1u);   // RNE
  return (u16)(r >> 16);
}
__device__ inline float bfu(uint32_t u) {            // bf16 bits (low 16) -> f32
  union { uint32_t x; float f; } z; z.x = u << 16; return z.f;
}

// ---------------------------------------------------------------------------
// Weight transpose+convert: W[K][128] fp32 -> WT[128][K] bf16 (LDS-tiled)
// ---------------------------------------------------------------------------
__global__ __launch_bounds__(256) void wtrans(const float* __restrict__ W,
                                              u16* __restrict__ WT, int K) {
  __shared__ float sh[64][33];
  const int k0 = blockIdx.x * 64, n0 = blockIdx.y * 32;
  const int t = threadIdx.x;
  {
    int r = t >> 3, c4 = t & 7;
#pragma unroll
    for (int p = 0; p < 2; ++p) {
      int row = p * 32 + r;
      float4 v = *(const float4*)&W[(size_t)(k0 + row) * 128 + n0 + c4 * 4];
      sh[row][c4 * 4 + 0] = v.x; sh[row][c4 * 4 + 1] = v.y;
      sh[row][c4 * 4 + 2] = v.z; sh[row][c4 * 4 + 3] = v.w;
    }
  }
  __syncthreads();
  int n = t >> 3, kq = t & 7;
  u16 pk[8];
#pragma unroll
  for (int j = 0; j < 8; ++j) pk[j] = f2bf(sh[kq * 8 + j][n]);
  uint4 o;
  o.x = (uint32_t)pk[0] | ((uint32_t)pk[1] << 16);
  o.y = (uint32_t)pk[2] | ((uint32_t)pk[3] << 16);
  o.z = (uint32_t)pk[4] | ((uint32_t)pk[5] << 16);
  o.w = (uint32_t)pk[6] | ((uint32_t)pk[7] << 16);
  *(uint4*)&WT[(size_t)(n0 + n) * K + k0 + kq * 8] = o;
}

// ---------------------------------------------------------------------------
// CSR build: count -> exclusive scan (merged, 2 blocks) -> fill
// ---------------------------------------------------------------------------
__global__ __launch_bounds__(256) void count_deg(const int* __restrict__ esrc,
                                                 const int* __restrict__ edst,
                                                 int* __restrict__ cntC,
                                                 int* __restrict__ cntP) {
  int i = blockIdx.x * 256 + threadIdx.x;
  if (i >= En) return;
  atomicAdd(&cntP[edst[i]], 1);
  atomicAdd(&cntC[esrc[i]], 1);
}

__global__ __launch_bounds__(256) void scan2(const int* __restrict__ cntP,
                                             const int* __restrict__ cntC,
                                             int* __restrict__ offP,
                                             int* __restrict__ offC,
                                             int* __restrict__ curP,
                                             int* __restrict__ curC) {
  __shared__ int sh[257];
  const int* cnt; int* off; int* cur; int n;
  if (blockIdx.x == 0) { cnt = cntP; off = offP; cur = curP; n = NPn; }
  else                 { cnt = cntC; off = offC; cur = curC; n = NCn; }
  int t = threadIdx.x;
  int chunk = n >> 8;
  int base = t * chunk;
  int s = 0;
#pragma unroll 4
  for (int i = 0; i < chunk; ++i) s += cnt[base + i];
  sh[t] = s;
  __syncthreads();
  if (t == 0) {
    int run = 0;
    for (int i = 0; i < 256; ++i) { int v = sh[i]; sh[i] = run; run += v; }
    sh[256] = run;
  }
  __syncthreads();
  int p = sh[t];
  for (int i = 0; i < chunk; ++i) {
    off[base + i] = p; cur[base + i] = p; p += cnt[base + i];
  }
  if (t == 255) off[n] = sh[256];
}

__global__ __launch_bounds__(256) void fill_adj(const int* __restrict__ esrc,
                                                const int* __restrict__ edst,
                                                int* __restrict__ curC,
                                                int* __restrict__ curP,
                                                int* __restrict__ adjC,
                                                int* __restrict__ adjP) {
  int i = blockIdx.x * 256 + threadIdx.x;
  if (i >= En) return;
  int s = esrc[i], d = edst[i];
  int p = atomicAdd(&curP[d], 1);
  adjP[p] = s;
  int q = atomicAdd(&curC[s], 1);
  adjC[q] = d;
}

// ---------------------------------------------------------------------------
// Split-K big projection GEMM v4: BM=64, BN=128, BK=64.
// Double-buffered A-LDS (2x8KB) -> ONE barrier per K-stage. All global loads
// issued at stage start so COMPUTE covers them before the pre-barrier vmcnt
// drain. A regs distance-2 (2 sets), B regs distance-1 (2 sets).
// ---------------------------------------------------------------------------
__global__ __launch_bounds__(256) void gemm_big_sk(const float* __restrict__ A,
                                                   const u16* __restrict__ BT,
                                                   float* __restrict__ part,
                                                   int K, int Kc) {
  __shared__ __align__(16) u16 aL[2 * 64 * 64];   // 16 KB
  const int t = threadIdx.x;
  const int wid = t >> 6, lane = t & 63;
  const int ln15 = lane & 15, lhi = lane >> 4;
  const int m0 = blockIdx.x * 64;
  const int kb0 = blockIdx.y * Kc;
  const int nIter = Kc >> 6;                      // even, >= 16
  const size_t M128 = (size_t)gridDim.x * 64 * 128;

  f32x4 acc[4][2] = {};

  const int arow = t >> 2, acq = t & 3;
  const float* Ap = &A[(size_t)(m0 + arow) * K + kb0 + acq * 16];
  const u16* Bp = &BT[(size_t)(wid * 32 + ln15) * K + kb0 + lhi * 8];
  const size_t BniStride = (size_t)16 * K;

#define LOAD_A(dst, koff)                                                      \
  { _Pragma("unroll") for (int i = 0; i < 4; ++i)                              \
      dst[i] = *(const float4*)(Ap + (koff) + i * 4); }
#define LOAD_B(dst, koff)                                                      \
  { _Pragma("unroll") for (int ni = 0; ni < 2; ++ni)                           \
    _Pragma("unroll") for (int ks = 0; ks < 2; ++ks)                           \
      dst[ni][ks] = *(const bf16x8*)(Bp + ni * BniStride + (koff) + ks * 32); }
#define STORE_A_LDS(src, b)                                                    \
  { u16 pk[16];                                                                \
    _Pragma("unroll") for (int i = 0; i < 4; ++i) {                            \
      pk[i*4+0] = f2bf(src[i].x); pk[i*4+1] = f2bf(src[i].y);                  \
      pk[i*4+2] = f2bf(src[i].z); pk[i*4+3] = f2bf(src[i].w); }                \
    uint4 w0, w1;                                                              \
    w0.x = (uint32_t)pk[0] | ((uint32_t)pk[1] << 16);                          \
    w0.y = (uint32_t)pk[2] | ((uint32_t)pk[3] << 16);                          \
    w0.z = (uint32_t)pk[4] | ((uint32_t)pk[5] << 16);                          \
    w0.w = (uint32_t)pk[6] | ((uint32_t)pk[7] << 16);                          \
    w1.x = (uint32_t)pk[8] | ((uint32_t)pk[9] << 16);                          \
    w1.y = (uint32_t)pk[10] | ((uint32_t)pk[11] << 16);                        \
    w1.z = (uint32_t)pk[12] | ((uint32_t)pk[13] << 16);                        \
    w1.w = (uint32_t)pk[14] | ((uint32_t)pk[15] << 16);                        \
    int sb = (b) * 8192 + arow * 128;                                          \
    int sw = (arow & 7) << 4;                                                  \
    *(uint4*)((char*)aL + sb + ((acq * 32) ^ sw)) = w0;                        \
    *(uint4*)((char*)aL + sb + ((acq * 32 + 16) ^ sw)) = w1; }
#define COMPUTE(b, bset)                                                       \
  { _Pragma("unroll") for (int ks = 0; ks < 2; ++ks) {                         \
      bf16x8 afr[4];                                                           \
      _Pragma("unroll") for (int mi = 0; mi < 4; ++mi) {                       \
        int r = mi * 16 + ln15;                                                \
        afr[mi] = *(const bf16x8*)((const char*)aL + (b) * 8192 + r * 128 +    \
                    ((ks * 64 + lhi * 16) ^ ((r & 7) << 4)));                  \
      }                                                                        \
      _Pragma("unroll") for (int mi = 0; mi < 4; ++mi)                         \
      _Pragma("unroll") for (int ni = 0; ni < 2; ++ni)                         \
        acc[mi][ni] = __builtin_amdgcn_mfma_f32_16x16x32_bf16(                 \
            afr[mi], bset[ni][ks], acc[mi][ni], 0, 0, 0);                      \
    } }

  float4 av0[4], av1[4];
  bf16x8 bv0[2][2], bv1[2][2];

  // prologue: tile0 -> buf0; tile1 staged in av1; B0 in bv0
  LOAD_A(av0, 0)
  LOAD_B(bv0, 0)
  STORE_A_LDS(av0, 0)
  LOAD_A(av1, 64)
  __syncthreads();

  for (int it = 0; it < nIter; it += 2) {
    // ---- stage it (parity 0): compute buf0 + bv0 ----
    STORE_A_LDS(av1, 1)                         // tile it+1 -> buf1
    if (it + 2 < nIter) LOAD_A(av0, (it + 2) * 64)
    LOAD_B(bv1, (it + 1) * 64)                  // B for stage it+1
    COMPUTE(0, bv0)
    __syncthreads();
    // ---- stage it+1 (parity 1): compute buf1 + bv1 ----
    if (it + 2 < nIter) {
      STORE_A_LDS(av0, 0)                       // tile it+2 -> buf0
      if (it + 3 < nIter) LOAD_A(av1, (it + 3) * 64)
      LOAD_B(bv0, (it + 2) * 64)                // B for stage it+2
    }
    COMPUTE(1, bv1)
    if (it + 2 < nIter) __syncthreads();
  }

  float* P = part + (size_t)blockIdx.y * M128;
#pragma unroll
  for (int mi = 0; mi < 4; ++mi) {
#pragma unroll
    for (int ni = 0; ni < 2; ++ni) {
      int col = wid * 32 + ni * 16 + ln15;
#pragma unroll
      for (int r = 0; r < 4; ++r) {
        int row = m0 + mi * 16 + lhi * 4 + r;
        P[(size_t)row * 128 + col] = acc[mi][ni][r];
      }
    }
  }
#undef LOAD_A
#undef LOAD_B
#undef STORE_A_LDS
#undef COMPUTE
}

// Combine split-K partials: out = sum_c part[c] + bias + addend
// Dual-write: fp32 (for lin_r GEMM input) + bf16 (for aggregation gathers)
__global__ __launch_bounds__(256) void gemm_combine(const float* __restrict__ part,
                                                    const float* __restrict__ bias,
                                                    const float* __restrict__ addend,
                                                    float* __restrict__ out,
                                                    u16* __restrict__ outH,
                                                    int M, int SK) {
  int i = blockIdx.x * 256 + threadIdx.x;
  int n4 = M * 32;
  if (i >= n4) return;
  size_t stride = (size_t)M * 128;
  f32x4 s = {};
  for (int c = 0; c < SK; ++c) s += *(const f32x4*)&part[c * stride + (size_t)i * 4];
  int col = (i * 4) & 127;
  f32x4 b = *(const f32x4*)&bias[col];
  f32x4 ad = *(const f32x4*)&addend[(size_t)i * 4];
  f32x4 r = s + b + ad;
  *(f32x4*)&out[(size_t)i * 4] = r;
  uint2 h;
  h.x = (uint32_t)f2bf(r[0]) | ((uint32_t)f2bf(r[1]) << 16);
  h.y = (uint32_t)f2bf(r[2]) | ((uint32_t)f2bf(r[3]) << 16);
  *(uint2*)&outH[(size_t)i * 4] = h;
}

// ---------------------------------------------------------------------------
// Small layer GEMM (fp32 SIMT, exact), register-prefetched staging.
// Optionally dual-writes a bf16 copy (for gathers downstream).
// ---------------------------------------------------------------------------
template <int RELU>
__global__ __launch_bounds__(256) void gemm_layer(const float* __restrict__ A1,
                                                  const float* __restrict__ A2,
                                                  const float* __restrict__ Wl,
                                                  const float* __restrict__ Wr,
                                                  const float* __restrict__ bias,
                                                  float* __restrict__ out,
                                                  u16* __restrict__ outH) {
  __shared__ float aT[32][33];
  __shared__ float wT[32][128];
  const int t = threadIdx.x;
  const int tx = t & 15, ty = t >> 4;
  const int m0 = blockIdx.x * 32;
  const int arow = t >> 3, ac = t & 7;
  const int wrow8 = t >> 5, wc = t & 31;
  float acc[2][8] = {};

  float4 a_v;
  float4 w_v[4];
  a_v = *(const float4*)&A1[(size_t)(m0 + arow) * 128 + ac * 4];
#pragma unroll
  for (int i = 0; i < 4; ++i)
    w_v[i] = *(const float4*)&Wl[(size_t)(i * 8 + wrow8) * 128 + wc * 4];

  for (int kc = 0; kc < 8; ++kc) {
    __syncthreads();
    aT[arow][ac * 4 + 0] = a_v.x; aT[arow][ac * 4 + 1] = a_v.y;
    aT[arow][ac * 4 + 2] = a_v.z; aT[arow][ac * 4 + 3] = a_v.w;
#pragma unroll
    for (int i = 0; i < 4; ++i) *(float4*)&wT[i * 8 + wrow8][wc * 4] = w_v[i];
    if (kc + 1 < 8) {
      int nk = kc + 1;
      const float* Asrc = (nk < 4) ? A1 : A2;
      const float* Wsrc = (nk < 4) ? Wl : Wr;
      int kb = (nk & 3) * 32;
      a_v = *(const float4*)&Asrc[(size_t)(m0 + arow) * 128 + kb + ac * 4];
#pragma unroll
      for (int i = 0; i < 4; ++i)
        w_v[i] = *(const float4*)&Wsrc[(size_t)(kb + i * 8 + wrow8) * 128 + wc * 4];
    }
    __syncthreads();
#pragma unroll
    for (int k = 0; k < 32; ++k) {
      float a0 = aT[ty * 2 + 0][k], a1 = aT[ty * 2 + 1][k];
      float4 w0 = *(const float4*)&wT[k][tx * 8];
      float4 w1 = *(const float4*)&wT[k][tx * 8 + 4];
      float w[8] = {w0.x, w0.y, w0.z, w0.w, w1.x, w1.y, w1.z, w1.w};
#pragma unroll
      for (int j = 0; j < 8; ++j) {
        acc[0][j] += a0 * w[j];
        acc[1][j] += a1 * w[j];
      }
    }
  }
#pragma unroll
  for (int i = 0; i < 2; ++i) {
    int row = m0 + ty * 2 + i;
    float o[8];
#pragma unroll
    for (int j = 0; j < 8; ++j) {
      float v = acc[i][j] + bias[tx * 8 + j];
      o[j] = RELU ? fmaxf(v, 0.f) : v;
    }
    float4 v0 = {o[0], o[1], o[2], o[3]}, v1 = {o[4], o[5], o[6], o[7]};
    *(float4*)&out[(size_t)row * 128 + tx * 8] = v0;
    *(float4*)&out[(size_t)row * 128 + tx * 8 + 4] = v1;
    if (outH) {
      uint4 h;
      h.x = (uint32_t)f2bf(o[0]) | ((uint32_t)f2bf(o[1]) << 16);
      h.y = (uint32_t)f2bf(o[2]) | ((uint32_t)f2bf(o[3]) << 16);
      h.z = (uint32_t)f2bf(o[4]) | ((uint32_t)f2bf(o[5]) << 16);
      h.w = (uint32_t)f2bf(o[6]) | ((uint32_t)f2bf(o[7]) << 16);
      *(uint4*)&outH[(size_t)row * 128 + tx * 8] = h;
    }
  }
}

// ---------------------------------------------------------------------------
// CSR mean aggregation over bf16 features (fp32 accumulation)
// ---------------------------------------------------------------------------
__global__ __launch_bounds__(256) void agg_mean_h(const int* __restrict__ adj,
                                                  const int* __restrict__ off,
                                                  const u16* __restrict__ Xh,
                                                  float* __restrict__ out, int ndst) {
  int w = blockIdx.x * 4 + (threadIdx.x >> 6);
  if (w >= ndst) return;
  int lane = threadIdx.x & 63;
  int q = lane >> 4, c = lane & 15;
  int s0 = off[w], deg = off[w + 1] - s0;
  f32x4 acc0 = {}, acc1 = {};
#define ACC8(v)                                                                \
  { acc0[0] += bfu((v).x & 0xffffu); acc0[1] += bfu((v).x >> 16);              \
    acc0[2] += bfu((v).y & 0xffffu); acc0[3] += bfu((v).y >> 16);              \
    acc1[0] += bfu((v).z & 0xffffu); acc1[1] += bfu((v).z >> 16);              \
    acc1[2] += bfu((v).w & 0xffffu); acc1[3] += bfu((v).w >> 16); }
  for (int base = 0; base < deg; base += 64) {
    int my = base + lane;
    int sv = (my < deg) ? adj[s0 + my] : 0;
    int cnt = min(64, deg - base);
    int jj = 0;
    for (; jj + 8 <= cnt; jj += 8) {
      int n0 = __shfl(sv, jj + q);
      int n1 = __shfl(sv, jj + 4 + q);
      uint4 v0 = *(const uint4*)&Xh[(size_t)n0 * 128 + c * 8];
      uint4 v1 = *(const uint4*)&Xh[(size_t)n1 * 128 + c * 8];
      ACC8(v0)
      ACC8(v1)
    }
    for (; jj + 4 <= cnt; jj += 4) {
      int n0 = __shfl(sv, jj + q);
      uint4 v0 = *(const uint4*)&Xh[(size_t)n0 * 128 + c * 8];
      ACC8(v0)
    }
    int r = cnt - jj;
    if (r > 0) {
      int n0 = __shfl(sv, min(jj + q, cnt - 1));
      if (q < r) {
        uint4 v0 = *(const uint4*)&Xh[(size_t)n0 * 128 + c * 8];
        ACC8(v0)
      }
    }
  }
#undef ACC8
#pragma unroll
  for (int j = 0; j < 4; ++j) {
    acc0[j] += __shfl_xor(acc0[j], 16);
    acc0[j] += __shfl_xor(acc0[j], 32);
    acc1[j] += __shfl_xor(acc1[j], 16);
    acc1[j] += __shfl_xor(acc1[j], 32);
  }
  if (q == 0) {
    float inv = 1.f / (float)max(deg, 1);
    acc0 *= inv; acc1 *= inv;
    *(f32x4*)&out[(size_t)w * 128 + c * 8] = acc0;
    *(f32x4*)&out[(size_t)w * 128 + c * 8 + 4] = acc1;
  }
}

// ---------------------------------------------------------------------------
// Edge classifier over bf16 features: 4 edges/wave, 16 B (8 bf16) per lane,
// fp32 products + 16-lane xor reduce.
// ---------------------------------------------------------------------------
__global__ __launch_bounds__(256) void edge_dot_h(const int* __restrict__ ls,
                                                  const int* __restrict__ ld,
                                                  const u16* __restrict__ aH,
                                                  const u16* __restrict__ bH,
                                                  float* __restrict__ o, int n) {
  int w = blockIdx.x * 4 + (threadIdx.x >> 6);
  int lane = threadIdx.x & 63;
  int q = lane >> 4, c = lane & 15;
  int e = w * 4 + q;
  if (e >= n) return;
  int s = ls[e], d = ld[e];
  uint4 va = *(const uint4*)&aH[(size_t)s * 128 + c * 8];
  uint4 vb = *(const uint4*)&bH[(size_t)d * 128 + c * 8];
  float p = bfu(va.x & 0xffffu) * bfu(vb.x & 0xffffu)
          + bfu(va.x >> 16)     * bfu(vb.x >> 16)
          + bfu(va.y & 0xffffu) * bfu(vb.y & 0xffffu)
          + bfu(va.y >> 16)     * bfu(vb.y >> 16)
          + bfu(va.z & 0xffffu) * bfu(vb.z & 0xffffu)
          + bfu(va.z >> 16)     * bfu(vb.z >> 16)
          + bfu(va.w & 0xffffu) * bfu(vb.w & 0xffffu)
          + bfu(va.w >> 16)     * bfu(vb.w >> 16);
#pragma unroll
  for (int m = 8; m; m >>= 1) p += __shfl_xor(p, m);
  if (c == 0) o[e] = p;
}

// ---------------------------------------------------------------------------
extern "C" void kernel_launch(void* const* d_in, const int* in_sizes, int n_in,
                              void* d_out, int out_size, void* d_ws, size_t ws_size,
                              hipStream_t stream) {
  const float* x_c    = (const float*)d_in[0];
  const float* x_p    = (const float*)d_in[1];
  const float* Wc     = (const float*)d_in[2];
  const float* bc     = (const float*)d_in[3];
  const float* Wp     = (const float*)d_in[4];
  const float* bp     = (const float*)d_in[5];
  const float* emb_c  = (const float*)d_in[6];
  const float* emb_p  = (const float*)d_in[7];
  const float* W1ep_l = (const float*)d_in[8];
  const float* b1ep   = (const float*)d_in[9];
  const float* W1ep_r = (const float*)d_in[10];
  const float* W1pc_l = (const float*)d_in[11];
  const float* b1pc   = (const float*)d_in[12];
  const float* W1pc_r = (const float*)d_in[13];
  const float* W2ep_l = (const float*)d_in[14];
  const float* b2ep   = (const float*)d_in[15];
  const float* W2ep_r = (const float*)d_in[16];
  const float* W2pc_l = (const float*)d_in[17];
  const float* b2pc   = (const float*)d_in[18];
  const float* W2pc_r = (const float*)d_in[19];
  const int* e_src    = (const int*)d_in[22];
  const int* e_dst    = (const int*)d_in[23];
  const int* l_src    = (const int*)d_in[24];
  const int* l_dst    = (const int*)d_in[25];

  size_t off = 0;
  auto alloc = [&](size_t bytes) -> void* {
    void* p = (char*)d_ws + off;
    off += (bytes + 255) & ~(size_t)255;
    return p;
  };
  float* xc    = (float*)alloc((size_t)NCn * Hn * 4);
  float* xp    = (float*)alloc((size_t)NPn * Hn * 4);
  float* aggP  = (float*)alloc((size_t)NPn * Hn * 4);
  float* aggC  = (float*)alloc((size_t)NCn * Hn * 4);
  float* hp    = (float*)alloc((size_t)NPn * Hn * 4);
  float* hc    = (float*)alloc((size_t)NCn * Hn * 4);
  float* hp2   = (float*)alloc((size_t)NPn * Hn * 4);
  float* hc2   = (float*)alloc((size_t)NCn * Hn * 4);
  u16*   xcH   = (u16*)alloc((size_t)NCn * Hn * 2);
  u16*   xpH   = (u16*)alloc((size_t)NPn * Hn * 2);
  u16*   hpH   = (u16*)alloc((size_t)NPn * Hn * 2);
  u16*   hcH   = (u16*)alloc((size_t)NCn * Hn * 2);
  u16*   hp2H  = (u16*)alloc((size_t)NPn * Hn * 2);
  u16*   hc2H  = (u16*)alloc((size_t)NCn * Hn * 2);
  u16*   WcT   = (u16*)alloc((size_t)Hn * NCn * 2);
  u16*   WpT   = (u16*)alloc((size_t)Hn * NPn * 2);
  float* partP = (float*)alloc((size_t)8 * NPn * Hn * 4);
  float* partC = (float*)alloc((size_t)4 * NCn * Hn * 4);
  int*   adjP  = (int*)alloc((size_t)En * 4);
  int*   adjC  = (int*)alloc((size_t)En * 4);
  int*   offP  = (int*)alloc((size_t)(NPn + 1) * 4);
  int*   offC  = (int*)alloc((size_t)(NCn + 1) * 4);
  int*   curP  = (int*)alloc((size_t)NPn * 4);
  int*   curC  = (int*)alloc((size_t)NCn * 4);
  int*   cnts  = (int*)alloc((size_t)(NPn + NCn) * 4);
  int*   cntP  = cnts;
  int*   cntC  = cnts + NPn;

  hipMemsetAsync(cnts, 0, (size_t)(NPn + NCn) * 4, stream);

  // CSR build
  count_deg<<<(En + 255) / 256, 256, 0, stream>>>(e_src, e_dst, cntC, cntP);
  scan2<<<2, 256, 0, stream>>>(cntP, cntC, offP, offC, curP, curC);
  fill_adj<<<(En + 255) / 256, 256, 0, stream>>>(e_src, e_dst, curC, curP, adjC, adjP);

  // input projections
  wtrans<<<dim3(NCn / 64, 4), 256, 0, stream>>>(Wc, WcT, NCn);
  wtrans<<<dim3(NPn / 64, 4), 256, 0, stream>>>(Wp, WpT, NPn);
  gemm_big_sk<<<dim3(NCn / 64, 4), 256, 0, stream>>>(x_c, WcT, partC, NCn, NCn / 4);
  gemm_big_sk<<<dim3(NPn / 64, 8), 256, 0, stream>>>(x_p, WpT, partP, NPn, NPn / 8);
  gemm_combine<<<(NCn * 32 + 255) / 256, 256, 0, stream>>>(partC, bc, emb_c, xc, xcH, NCn, 4);
  gemm_combine<<<(NPn * 32 + 255) / 256, 256, 0, stream>>>(partP, bp, emb_p, xp, xpH, NPn, 8);

  // layer 1 (bf16 gathers, fp32 GEMM; writes bf16 copies for layer-2 gathers)
  agg_mean_h<<<NPn / 4, 256, 0, stream>>>(adjP, offP, xcH, aggP, NPn);
  agg_mean_h<<<NCn / 4, 256, 0, stream>>>(adjC, offC, xpH, aggC, NCn);
  gemm_layer<1><<<NPn / 32, 256, 0, stream>>>(aggP, xp, W1ep_l, W1ep_r, b1ep, hp, hpH);
  gemm_layer<1><<<NCn / 32, 256, 0, stream>>>(aggC, xc, W1pc_l, W1pc_r, b1pc, hc, hcH);

  // layer 2 (bf16 gathers; bf16 copies for the classifier)
  agg_mean_h<<<NPn / 4, 256, 0, stream>>>(adjP, offP, hcH, aggP, NPn);
  agg_mean_h<<<NCn / 4, 256, 0, stream>>>(adjC, offC, hpH, aggC, NCn);
  gemm_layer<0><<<NPn / 32, 256, 0, stream>>>(aggP, hp, W2ep_l, W2ep_r, b2ep, hp2, hp2H);
  gemm_layer<0><<<NCn / 32, 256, 0, stream>>>(aggC, hc, W2pc_l, W2pc_r, b2pc, hc2, hc2H);

  // classifier (bf16 gathers, fp32 dot)
  edge_dot_h<<<(ELn + 15) / 16, 256, 0, stream>>>(l_src, l_dst, hc2H, hp2H,
                                                  (float*)d_out, ELn);
}